// Round 4
// baseline (538.824 us; speedup 1.0000x reference)
//
#include <hip/hip_runtime.h>
#include <stdint.h>

// KNN BC policy: B=1024 x D=512 queries vs N=100000 bank, top-16 L2, mean of acts [1024,32].
// R4 = R3 with ONE change: fragment LDS loads via half8* pointer arithmetic so the
// compiler can prove 16B alignment and emit ds_read_b128 (R3's char*+XOR byte offsets
// scalarized to ds_read_u16 -> VALUBusy 90%). Structure otherwise identical.

#define NQ     1024
#define DIM    512
#define NB     100000
#define NPAD   100352          // 392 * 256
#define NBLK   392             // n-blocks of 256 rows
#define ADIM   32
#define KNB    16
#define NCAND  (NBLK * 8)      // 3136 candidates per query
#define QUARTER (NCAND / 4)    // 784 per wave in topk

typedef __attribute__((ext_vector_type(8)))  _Float16 half8;
typedef __attribute__((ext_vector_type(16))) float f32x16;

__device__ inline int   f2i(float f) { union { float f; int i; } u; u.f = f; return u.i; }
__device__ inline float i2f(int i)   { union { int i; float f; } u; u.i = i; return u.f; }

__device__ inline void gload16(const void* g, void* l) {
  __builtin_amdgcn_global_load_lds(
      (const __attribute__((address_space(1))) unsigned int*)g,
      (__attribute__((address_space(3))) unsigned int*)l, 16, 0, 0);
}

// ---------------- conversion + norms ----------------
__global__ __launch_bounds__(256) void convert_bank_kernel(
    const float* __restrict__ bank, _Float16* __restrict__ bank16,
    float* __restrict__ b2) {
  const int row  = blockIdx.x * 4 + (threadIdx.x >> 6);
  const int lane = threadIdx.x & 63;
  if (row < NB) {
    const float* src = bank + (size_t)row * DIM + lane * 8;
    const float4 a = ((const float4*)src)[0];
    const float4 b = ((const float4*)src)[1];
    float ss = a.x*a.x + a.y*a.y + a.z*a.z + a.w*a.w
             + b.x*b.x + b.y*b.y + b.z*b.z + b.w*b.w;
    #pragma unroll
    for (int o = 32; o; o >>= 1) ss += __shfl_xor(ss, o);
    half8 o8;
    o8[0]=(_Float16)a.x; o8[1]=(_Float16)a.y; o8[2]=(_Float16)a.z; o8[3]=(_Float16)a.w;
    o8[4]=(_Float16)b.x; o8[5]=(_Float16)b.y; o8[6]=(_Float16)b.z; o8[7]=(_Float16)b.w;
    *(half8*)(bank16 + (size_t)row * DIM + lane * 8) = o8;
    if (lane == 0) b2[row] = ss;
  } else {
    half8 z = {0,0,0,0,0,0,0,0};
    *(half8*)(bank16 + (size_t)row * DIM + lane * 8) = z;
    if (lane == 0) b2[row] = 1e30f;   // pad rows never selected
  }
}

__global__ __launch_bounds__(256) void convert_obs_kernel(
    const float* __restrict__ obs, _Float16* __restrict__ o16) {
  const int row  = blockIdx.x * 4 + (threadIdx.x >> 6);
  const int lane = threadIdx.x & 63;
  const float* src = obs + (size_t)row * DIM + lane * 8;
  const float4 a = ((const float4*)src)[0];
  const float4 b = ((const float4*)src)[1];
  half8 o8;
  o8[0]=(_Float16)a.x; o8[1]=(_Float16)a.y; o8[2]=(_Float16)a.z; o8[3]=(_Float16)a.w;
  o8[4]=(_Float16)b.x; o8[5]=(_Float16)b.y; o8[6]=(_Float16)b.z; o8[7]=(_Float16)b.w;
  *(half8*)(o16 + (size_t)row * DIM + lane * 8) = o8;
}

// ---------------- swapped-operand GEMM + in-register top-8 ----------------
// Block: 256 n-rows x 128 queries. 8 waves = 2 (n-half) x 4 (q-group of 32).
// acc[s] = mfma_32x32x16(bank_frag, obs_frag): D col = lane&31 = query,
// row = (reg&3)+8*(reg>>2)+4*(lane>>5) = n within 32-subtile.
// score s = 0.5*b2[n] - dot  (monotone in d2); keep per-lane smallest-8.
__global__ __launch_bounds__(512) void gemm_select_kernel(
    const _Float16* __restrict__ A16,   // bank fp16 [NPAD][512]
    const _Float16* __restrict__ B16,   // obs  fp16 [1024][512]
    const float* __restrict__ b2,
    float2* __restrict__ cand) {
  __shared__ char smem[32768 + 16384 + 1024];
  const half8* As8 = (const half8*)smem;              // [256 rows][8 chunks] swizzled
  const half8* Bs8 = (const half8*)(smem + 32768);    // [128 rows][8 chunks] swizzled
  float*  b2s  = (float*)(smem + 32768 + 16384);      // [256]
  float2* mbuf = (float2*)smem;                       // epilogue reuse (16 KB)

  const int tid = threadIdx.x;
  const int l   = tid & 63;
  const int w   = tid >> 6;
  const int wq  = w & 3;       // query group (32 queries)
  const int wnh = w >> 2;      // n half (128 rows)
  const int nblk = blockIdx.x;
  const int qblk = blockIdx.y;
  const int n0  = nblk * 256;
  const int q0g = qblk * 128;

  if (tid < 256) b2s[tid] = b2[n0 + tid];

  f32x16 acc[4];
  #pragma unroll
  for (int s = 0; s < 4; ++s)
    #pragma unroll
    for (int r = 0; r < 16; ++r) acc[s][r] = 0.f;

  // staging: wave-uniform LDS dest (HW adds lane*16); inverse-swizzled global src
  const int srw = l >> 3;                      // row within 8-row stage group
  const int sg  = (l & 7) ^ srw;               // inverse-swizzled k-chunk
  const size_t aoff = (size_t)(n0  + w * 32 + srw) * DIM + sg * 8;
  const size_t boff = (size_t)(q0g + w * 16 + srw) * DIM + sg * 8;

  const int rl = l & 31;
  const int kl = l >> 5;
  const int sw = rl & 7;                       // loop-invariant swizzle term

  for (int kt = 0; kt < 8; ++kt) {
    const int k0 = kt * 64;
    #pragma unroll
    for (int j = 0; j < 4; ++j)
      gload16(A16 + aoff + (size_t)j * 8 * DIM + k0, (char*)smem + (w * 4 + j) * 1024);
    #pragma unroll
    for (int j = 0; j < 2; ++j)
      gload16(B16 + boff + (size_t)j * 8 * DIM + k0, (char*)smem + 32768 + (w * 2 + j) * 1024);
    __syncthreads();

    const int br = wq * 32 + rl;               // obs row (query)
    #pragma unroll
    for (int kk = 0; kk < 4; ++kk) {
      const int cl = kk * 2 + kl;              // logical 16B k-chunk 0..7
      const half8 bf = Bs8[br * 8 + (cl ^ sw)];
      #pragma unroll
      for (int s = 0; s < 4; ++s) {
        const int ar = wnh * 128 + s * 32 + rl;  // bank row within block
        const half8 af = As8[ar * 8 + (cl ^ sw)];
        acc[s] = __builtin_amdgcn_mfma_f32_32x32x16_f16(af, bf, acc[s], 0, 0, 0);
      }
    }
    __syncthreads();
  }

  // ---- in-register selection: per-lane smallest-8 over 64 n-scores (one query) ----
  float ts[8]; int ti[8];
  #pragma unroll
  for (int i = 0; i < 8; ++i) { ts[i] = 1e38f; ti[i] = -1; }
  const int rbase = 4 * kl;
  #pragma unroll
  for (int s = 0; s < 4; ++s) {
    #pragma unroll
    for (int r = 0; r < 16; ++r) {
      const int nl = wnh * 128 + s * 32 + (r & 3) + 8 * (r >> 2) + rbase;
      const float sc = fmaf(0.5f, b2s[nl], -acc[s][r]);
      if (sc < ts[7]) {
        float cs = sc; int ci = n0 + nl;
        #pragma unroll
        for (int p = 0; p < 8; ++p) {
          if (cs < ts[p]) {
            float tf = ts[p]; ts[p] = cs; cs = tf;
            int   tt = ti[p]; ti[p] = ci; ci = tt;
          }
        }
      }
    }
  }

  // ---- lane-pair (l ^ 32) head-merge: top-8 of 16, written to mbuf ----
  float2* mrow = mbuf + ((wq * 2 + wnh) * 32 + rl) * 8;
  for (int k = 0; k < 8; ++k) {
    const float ov = __shfl_xor(ts[0], 32);
    const int   oi = __shfl_xor(ti[0], 32);
    const bool mine = (ts[0] < ov) || (ts[0] == ov && kl == 0);
    const float wv = mine ? ts[0] : ov;
    const int   wi = mine ? ti[0] : oi;
    if (mine) {
      #pragma unroll
      for (int p = 0; p < 7; ++p) { ts[p] = ts[p+1]; ti[p] = ti[p+1]; }
      ts[7] = 1e38f; ti[7] = -1;
    }
    if (kl == 0) mrow[k] = make_float2(wv, i2f(wi));
  }
  __syncthreads();

  // ---- cross-n-half merge (sorted 8+8 -> 8) + global store ----
  if (w < 4 && l < 32) {
    const float2* pa = mbuf + ((w * 2 + 0) * 32 + l) * 8;
    const float2* pb = mbuf + ((w * 2 + 1) * 32 + l) * 8;
    float av[8], bv[8]; int ai[8], bi[8];
    #pragma unroll
    for (int j = 0; j < 8; ++j) {
      const float2 ta = pa[j]; av[j] = ta.x; ai[j] = f2i(ta.y);
      const float2 tb = pb[j]; bv[j] = tb.x; bi[j] = f2i(tb.y);
    }
    float2* outp = cand + ((size_t)(q0g + w * 32 + l) * NBLK + nblk) * 8;
    for (int k = 0; k < 8; ++k) {
      const bool ta = (av[0] <= bv[0]);
      outp[k] = make_float2(ta ? av[0] : bv[0], i2f(ta ? ai[0] : bi[0]));
      if (ta) {
        #pragma unroll
        for (int p = 0; p < 7; ++p) { av[p] = av[p+1]; ai[p] = ai[p+1]; }
        av[7] = 1e38f;
      } else {
        #pragma unroll
        for (int p = 0; p < 7; ++p) { bv[p] = bv[p+1]; bi[p] = bi[p+1]; }
        bv[7] = 1e38f;
      }
    }
  }
}

// ---------------- per-query candidate merge + exact rerank ----------------
__global__ __launch_bounds__(256) void topk_kernel(
    const float2* __restrict__ cand, const float* __restrict__ obs,
    const float* __restrict__ bank, const float* __restrict__ acts,
    float* __restrict__ out) {
  __shared__ float2 lc[NCAND];       // 25088 B
  __shared__ float2 wtop[128];
  __shared__ int   selidx[32];
  __shared__ float exd[32];
  __shared__ int   sel2[16];
  const int q    = blockIdx.x;
  const int tid  = threadIdx.x;
  const int lane = tid & 63;
  const int w    = tid >> 6;

  for (int i = tid; i < NCAND; i += 256) lc[i] = cand[(size_t)q * NCAND + i];
  __syncthreads();

  // per-wave quarter: per-lane sorted top-10, then 32 head-extractions
  float ts[10]; int ti[10];
  #pragma unroll
  for (int i = 0; i < 10; ++i) { ts[i] = 1e38f; ti[i] = -1; }
  for (int i = w * QUARTER + lane; i < (w + 1) * QUARTER; i += 64) {
    const float2 e = lc[i];
    const float s = e.x;
    if (s < ts[9]) {
      float cs = s; int ci = f2i(e.y);
      #pragma unroll
      for (int pp = 0; pp < 10; ++pp) {
        if (cs < ts[pp]) {
          float tf = ts[pp]; ts[pp] = cs; cs = tf;
          int   tt = ti[pp]; ti[pp] = ci; ci = tt;
        }
      }
    }
  }
  for (int k = 0; k < 32; ++k) {
    float bv = ts[0]; int bi = ti[0]; int bl = lane;
    #pragma unroll
    for (int o = 32; o; o >>= 1) {
      float ov = __shfl_xor(bv, o); int oi = __shfl_xor(bi, o); int ol = __shfl_xor(bl, o);
      if (ov < bv || (ov == bv && ol < bl)) { bv = ov; bi = oi; bl = ol; }
    }
    if (lane == bl) {
      #pragma unroll
      for (int pp = 0; pp < 9; ++pp) { ts[pp] = ts[pp+1]; ti[pp] = ti[pp+1]; }
      ts[9] = 1e38f; ti[9] = -1;
    }
    if (lane == 0) wtop[w * 32 + k] = make_float2(bv, i2f(bi));
  }
  __syncthreads();

  // wave 0: top-32 of the 128 wave winners
  if (w == 0) {
    float2 e0 = wtop[lane], e1 = wtop[64 + lane];
    float s0 = e0.x, s1 = e1.x;
    int   i0 = f2i(e0.y), i1 = f2i(e1.y);
    if (s1 < s0) { float tf = s0; s0 = s1; s1 = tf; int tt = i0; i0 = i1; i1 = tt; }
    for (int k = 0; k < 32; ++k) {
      float bv = s0; int bi = i0; int bl = lane;
      #pragma unroll
      for (int o = 32; o; o >>= 1) {
        float ov = __shfl_xor(bv, o); int oi = __shfl_xor(bi, o); int ol = __shfl_xor(bl, o);
        if (ov < bv || (ov == bv && ol < bl)) { bv = ov; bi = oi; bl = ol; }
      }
      if (lane == bl) { s0 = s1; i0 = i1; s1 = 1e38f; i1 = -1; }
      if (lane == 0) selidx[k] = bi;
    }
  }
  __syncthreads();

  // exact fp32 distances for the 32 candidates (one wave per candidate, round-robin)
  const float* qp = obs + (size_t)q * DIM + lane * 8;
  const float4 qa = ((const float4*)qp)[0];
  const float4 qb = ((const float4*)qp)[1];
  for (int c2 = w; c2 < 32; c2 += 4) {
    const int idx = selidx[c2];
    const float* bp_ = bank + (size_t)idx * DIM + lane * 8;
    const float4 ba = ((const float4*)bp_)[0];
    const float4 bb = ((const float4*)bp_)[1];
    const float d0 = qa.x-ba.x, d1 = qa.y-ba.y, d2 = qa.z-ba.z, d3 = qa.w-ba.w;
    const float d4 = qb.x-bb.x, d5 = qb.y-bb.y, d6 = qb.z-bb.z, d7 = qb.w-bb.w;
    float ss = d0*d0 + d1*d1 + d2*d2 + d3*d3 + d4*d4 + d5*d5 + d6*d6 + d7*d7;
    #pragma unroll
    for (int o = 32; o; o >>= 1) ss += __shfl_xor(ss, o);
    if (lane == 0) exd[c2] = ss;
  }
  __syncthreads();

  // exact top-16 of 32
  if (w == 0) {
    const float v  = (lane < 32) ? exd[lane] : 1e38f;
    const int   id = (lane < 32) ? selidx[lane] : -1;
    float lastv = -1e38f; int lastp = -1;
    for (int k = 0; k < 16; ++k) {
      float bv = 1e38f; int bi = -1; int bp = 64;
      const bool gt = (v > lastv) || (v == lastv && lane > lastp);
      if (gt) { bv = v; bi = id; bp = lane; }
      #pragma unroll
      for (int o = 32; o; o >>= 1) {
        float ov = __shfl_xor(bv, o); int oi = __shfl_xor(bi, o); int op = __shfl_xor(bp, o);
        if (ov < bv || (ov == bv && op < bp)) { bv = ov; bi = oi; bp = op; }
      }
      if (lane == 0) sel2[k] = bi;
      lastv = bv; lastp = bp;
    }
  }
  __syncthreads();

  if (tid < ADIM) {
    float s = 0.f;
    #pragma unroll
    for (int t2 = 0; t2 < KNB; ++t2) s += acts[(size_t)sel2[t2] * ADIM + tid];
    out[(size_t)q * ADIM + tid] = s * (1.0f / KNB);
  }
}

// ---------------- host launch ----------------
extern "C" void kernel_launch(void* const* d_in, const int* in_sizes, int n_in,
                              void* d_out, int out_size, void* d_ws, size_t ws_size,
                              hipStream_t stream) {
  const float* obs  = (const float*)d_in[0];
  const float* bank = (const float*)d_in[1];
  const float* acts = (const float*)d_in[2];
  float* out = (float*)d_out;
  char* ws = (char*)d_ws;

  size_t off = 0;
  auto take = [&](size_t b) { size_t o = off; off += (b + 255) & ~(size_t)255; return o; };
  const size_t off_b16  = take((size_t)NPAD * DIM * 2);          // 102.8 MB
  const size_t off_o16  = take((size_t)NQ * DIM * 2);            // 1 MB
  const size_t off_b2   = take((size_t)NPAD * 4);                // 0.4 MB
  const size_t off_cand = take((size_t)NQ * NCAND * 8);          // 25.7 MB

  _Float16* bank16 = (_Float16*)(ws + off_b16);
  _Float16* obs16  = (_Float16*)(ws + off_o16);
  float*  b2   = (float*)(ws + off_b2);
  float2* cand = (float2*)(ws + off_cand);

  convert_bank_kernel<<<NPAD / 4, 256, 0, stream>>>(bank, bank16, b2);
  convert_obs_kernel<<<NQ / 4, 256, 0, stream>>>(obs, obs16);
  gemm_select_kernel<<<dim3(NBLK, NQ / 128), 512, 0, stream>>>(bank16, obs16, b2, cand);
  topk_kernel<<<NQ, 256, 0, stream>>>(cand, obs, bank, acts, out);
}